// Round 18
// baseline (232.719 us; speedup 1.0000x reference)
//
#include <hip/hip_runtime.h>

#define NPIX   65536          // B*H*W
#define CCH    64
#define KCODE  1024
#define HW     4096
#define Q_ELEMS 4194304
#define LOSS0_OFF 4194304
#define LOSS1_OFF 4194305
#define IDX_OFF   4194306
#define BPX    128            // pixels per block (4 waves x 32 rows)
#define NTILE  32             // 32 code-tiles of 32
#define THRF   2e-3f          // >=4x the deterministic |key - d_np + szz| bound
#define QCAP   1024

typedef _Float16 half8 __attribute__((ext_vector_type(8)));
typedef float    f32x16 __attribute__((ext_vector_type(16)));

// numpy pairwise_sum middle branch for n=64 on squares (bit-exact np.sum(x*x))
template <typename F>
__device__ __forceinline__ float np_pairwise64_sq(F v) {
    float r[8];
#pragma unroll
    for (int j = 0; j < 8; ++j) r[j] = __fmul_rn(v(j), v(j));
#pragma unroll
    for (int i = 8; i < 64; i += 8) {
#pragma unroll
        for (int j = 0; j < 8; ++j)
            r[j] = __fadd_rn(r[j], __fmul_rn(v(i + j), v(i + j)));
    }
    return __fadd_rn(
        __fadd_rn(__fadd_rn(r[0], r[1]), __fadd_rn(r[2], r[3])),
        __fadd_rn(__fadd_rn(r[4], r[5]), __fadd_rn(r[6], r[7])));
}

// prep: se (np chain, unchanged values) + B-pack (fp16 of emb in MFMA-frag
// order: frag(tile,s) lane l elem i  <->  e[tile*32+(l&31)][16s+8*(l>>5)+i]).
// Pairing note: A uses the SAME (h,i)->k map, so the contraction is correct
// under any HW k-slot permutation (it cancels).
__global__ void prep_kernel(const float* __restrict__ emb,
                            float* __restrict__ se, half8* __restrict__ bpk,
                            float* __restrict__ out) {
    const int tid = blockIdx.x * 256 + threadIdx.x;   // 0..8191
    const int tile = tid >> 8, s = (tid >> 6) & 3, lane = tid & 63;
    const int n = tile * 32 + (lane & 31);
    const int h = lane >> 5;
    const float* er = emb + (size_t)n * CCH;
    half8 v;
#pragma unroll
    for (int i = 0; i < 8; ++i) v[i] = (_Float16)er[16 * s + 8 * h + i];
    bpk[(tile * 4 + s) * 64 + lane] = v;
    if (tid < KCODE) {
        const float* e = emb + (size_t)tid * CCH;
        se[tid] = np_pairwise64_sq([&](int i) { return e[i]; });
    }
    if (tid == 0) { out[LOSS0_OFF] = 0.f; out[LOSS1_OFF] = 0.f; }
}

// main: MFMA filter (fp16, 2 sweeps) + exact fp32 verify of ~1.5 cand/pixel.
// Exactness: idx/q/losses all come from the IDENTICAL np fp32 chains as the
// 130us R8 kernel; MFMA only prunes candidates with a >=4x-margin bound.
// C/D layout (HW-verified m74/m101): col=lane&31, row=(r&3)+8*(r>>2)+4*(lane>>5).
__launch_bounds__(256, 3)
__global__ void vq_kernel(const float* __restrict__ z,
                          const float* __restrict__ emb,
                          const float* __restrict__ se,
                          const half8* __restrict__ bpk,
                          float* __restrict__ out) {
    __shared__ float s_szz[BPX];
    __shared__ unsigned long long s_best[BPX];
    __shared__ unsigned s_q[QCAP];
    __shared__ unsigned s_qn;
    __shared__ unsigned s_k[BPX];
    __shared__ float s_red[4];

    const int t = threadIdx.x, lane = t & 63, w = t >> 6;
    const int P0 = blockIdx.x * BPX;
    const int b = P0 >> 12, hw0 = P0 & 4095;
    const float* zbase = z + (size_t)b * CCH * HW + hw0;   // zbase[c*HW + pxl]

    if (t < BPX) {
        s_szz[t] = np_pairwise64_sq([&](int i) { return zbase[(size_t)i * HW + t]; });
        s_best[t] = ~0ULL;
    }
    if (t == 0) s_qn = 0u;
    __syncthreads();

    // A-frags: fp16(z) for this wave's 32 pixel-rows; slot (h,i) -> c=16s+8h+i
    const int row = lane & 31, h = lane >> 5;
    const float* zp = zbase + w * 32 + row;                // + c*HW
    half8 A[4];
#pragma unroll
    for (int s = 0; s < 4; ++s)
#pragma unroll
        for (int i = 0; i < 8; ++i)
            A[s][i] = (_Float16)zp[(size_t)(16 * s + 8 * h + i) * HW];

    // ---- sweep 1: rmin[r] = min over all codes of key = se_k - 2*dot~ ----
    float rmin[16];
#pragma unroll
    for (int r = 0; r < 16; ++r) rmin[r] = 1e30f;

    for (int tile = 0; tile < NTILE; ++tile) {
        f32x16 acc;
#pragma unroll
        for (int r = 0; r < 16; ++r) acc[r] = 0.f;
#pragma unroll
        for (int s = 0; s < 4; ++s)
            acc = __builtin_amdgcn_mfma_f32_32x32x16_f16(
                A[s], bpk[(tile * 4 + s) * 64 + lane], acc, 0, 0, 0);
        const float sev = se[tile * 32 + (lane & 31)];
#pragma unroll
        for (int r = 0; r < 16; ++r) {
            const float key = __builtin_fmaf(-2.f, acc[r], sev);
            rmin[r] = fminf(rmin[r], key);
        }
    }
    // cross-lane: lanes 0..31 (and 32..63) share rows per reg -> xor<=16 reduce
#pragma unroll
    for (int m = 1; m <= 16; m <<= 1)
#pragma unroll
        for (int r = 0; r < 16; ++r)
            rmin[r] = fminf(rmin[r], __shfl_xor(rmin[r], m, 64));

    // ---- sweep 2: bit-identical recompute, push candidates <= min + THR ----
    for (int tile = 0; tile < NTILE; ++tile) {
        f32x16 acc;
#pragma unroll
        for (int r = 0; r < 16; ++r) acc[r] = 0.f;
#pragma unroll
        for (int s = 0; s < 4; ++s)
            acc = __builtin_amdgcn_mfma_f32_32x32x16_f16(
                A[s], bpk[(tile * 4 + s) * 64 + lane], acc, 0, 0, 0);
        const float sev = se[tile * 32 + (lane & 31)];
#pragma unroll
        for (int r = 0; r < 16; ++r) {
            const float key = __builtin_fmaf(-2.f, acc[r], sev);
            if (key <= rmin[r] + THRF) {                    // ~1.5 per pixel
                const int pxl = w * 32 + (r & 3) + 8 * (r >> 2) + 4 * h;
                const unsigned k = (unsigned)(tile * 32 + (lane & 31));
                const unsigned qi = atomicAdd(&s_qn, 1u);
                if (qi < QCAP) s_q[qi] = ((unsigned)pxl << 10) | k;
            }
        }
    }
    __syncthreads();

    // ---- exact verify: np fp32 chain (identical to R8), packed-u64 min ----
    {
        unsigned qn = s_qn; if (qn > QCAP) qn = QCAP;
        for (unsigned i = t; i < qn; i += 256) {
            const unsigned e = s_q[i];
            const int pxl = (int)(e >> 10), k = (int)(e & 1023u);
            const float* zc = zbase + pxl;
            const float* ek = emb + (size_t)k * CCH;
            float a = 0.f;
#pragma unroll 8
            for (int c = 0; c < CCH; ++c)
                a = __builtin_fmaf(zc[(size_t)c * HW], ek[c], a);  // same chain as R8
            const float d = __fsub_rn(__fadd_rn(s_szz[pxl], se[k]), __fadd_rn(a, a));
            atomicMin(&s_best[pxl],
                      ((unsigned long long)__float_as_uint(d) << 32) | (unsigned)k);
        }
    }
    __syncthreads();

    if (t < BPX) {
        const unsigned k = (unsigned)s_best[t];   // low 32 bits = argmin (first-index)
        s_k[t] = k;
        out[IDX_OFF + P0 + t] = (float)k;
    }
    __syncthreads();

    // ---- epilogue x8: EXACT R8 16-px tile procedure (same addend multiset) ----
#pragma unroll 1
    for (int ht = 0; ht < 8; ++ht) {
        float lsum = 0.f;
        {
            const int p = t & 15, g = t >> 4;
            const int pxl = (ht << 4) + p;
            const int k = (int)s_k[pxl];
#pragma unroll
            for (int u = 0; u < 4; ++u) {
                const int c = g + (u << 4);
                float e    = emb[(size_t)k * CCH + c];
                float zc   = zbase[(size_t)c * HW + pxl];
                float diff = __fsub_rn(e, zc);             // STE rounding as in R8
                out[((size_t)(b * CCH + c)) * HW + hw0 + pxl] = __fadd_rn(zc, diff);
                lsum = __builtin_fmaf(diff, diff, lsum);
            }
        }
#pragma unroll
        for (int off = 32; off > 0; off >>= 1) lsum += __shfl_down(lsum, off, 64);
        if (lane == 0) s_red[w] = lsum;
        __syncthreads();
        if (t == 0) {
            float v = (s_red[0] + s_red[1] + s_red[2] + s_red[3]) * (1.0f / (float)Q_ELEMS);
            atomicAdd(out + LOSS0_OFF, v);   // codebook_loss
            atomicAdd(out + LOSS1_OFF, v);   // commitment_loss (same forward value)
        }
        __syncthreads();
    }
}

extern "C" void kernel_launch(void* const* d_in, const int* in_sizes, int n_in,
                              void* d_out, int out_size, void* d_ws, size_t ws_size,
                              hipStream_t stream) {
    const float* z   = (const float*)d_in[0];
    const float* emb = (const float*)d_in[1];
    float* out = (float*)d_out;
    float* se  = (float*)d_ws;                     // 1024 f32
    half8* bpk = (half8*)(se + KCODE);             // 128 KB fp16 B-frags

    prep_kernel<<<dim3(32), dim3(256), 0, stream>>>(emb, se, bpk, out);
    vq_kernel<<<dim3(NPIX / BPX), dim3(256), 0, stream>>>(z, emb, se, bpk, out);
}

// Round 19
// 195.417 us; speedup vs baseline: 1.1909x; 1.1909x over previous
//
#include <hip/hip_runtime.h>

#define NPIX   65536          // B*H*W
#define CCH    64
#define KCODE  1024
#define HW     4096
#define Q_ELEMS 4194304
#define LOSS0_OFF 4194304
#define LOSS1_OFF 4194305
#define IDX_OFF   4194306
#define BPX    32             // pixels per block = one 32-row MFMA block
#define TPW    8              // code-tiles per wave (4 waves x 8 = all 32 tiles)
#define THRF   2e-3f          // ~25x the deterministic fp16 key-error bound
#define QCAP   512            // expected ~70 candidates/block

typedef _Float16 half8 __attribute__((ext_vector_type(8)));
typedef float    f32x16 __attribute__((ext_vector_type(16)));

// lossless order-preserving f32<->u32 bijection (for LDS atomicMin on keys)
__device__ __forceinline__ unsigned f32_sort(float f) {
    unsigned b = __float_as_uint(f);
    return (b & 0x80000000u) ? ~b : (b | 0x80000000u);
}
__device__ __forceinline__ float f32_unsort(unsigned u) {
    return (u & 0x80000000u) ? __uint_as_float(u & 0x7fffffffu)
                             : __uint_as_float(~u);
}

// numpy pairwise_sum middle branch for n=64 on squares (bit-exact np.sum(x*x))
template <typename F>
__device__ __forceinline__ float np_pairwise64_sq(F v) {
    float r[8];
#pragma unroll
    for (int j = 0; j < 8; ++j) r[j] = __fmul_rn(v(j), v(j));
#pragma unroll
    for (int i = 8; i < 64; i += 8) {
#pragma unroll
        for (int j = 0; j < 8; ++j)
            r[j] = __fadd_rn(r[j], __fmul_rn(v(i + j), v(i + j)));
    }
    return __fadd_rn(
        __fadd_rn(__fadd_rn(r[0], r[1]), __fadd_rn(r[2], r[3])),
        __fadd_rn(__fadd_rn(r[4], r[5]), __fadd_rn(r[6], r[7])));
}

// prep: se (np chain) + fp16 B-frag pack (same (h,i)->c map as A => pairing
// cancels any HW k-slot permutation). Unchanged from the passing R18.
__global__ void prep_kernel(const float* __restrict__ emb,
                            float* __restrict__ se, half8* __restrict__ bpk,
                            float* __restrict__ out) {
    const int tid = blockIdx.x * 256 + threadIdx.x;   // 0..8191
    const int tile = tid >> 8, s = (tid >> 6) & 3, lane = tid & 63;
    const int n = tile * 32 + (lane & 31);
    const int h = lane >> 5;
    const float* er = emb + (size_t)n * CCH;
    half8 v;
#pragma unroll
    for (int i = 0; i < 8; ++i) v[i] = (_Float16)er[16 * s + 8 * h + i];
    bpk[(tile * 4 + s) * 64 + lane] = v;
    if (tid < KCODE) {
        const float* e = emb + (size_t)tid * CCH;
        se[tid] = np_pairwise64_sq([&](int i) { return e[i]; });
    }
    if (tid == 0) { out[LOSS0_OFF] = 0.f; out[LOSS1_OFF] = 0.f; }
}

// main: R18's proven filter-verify, re-shaped for TLP. R18 was grid-limited:
// 512 blocks x 4 waves = 2 waves/SIMD device-wide -> 96% stall (MfmaUtil 4%,
// VALUBusy 7%). Now: 32 px/block, 4 waves split the 32 code-tiles (8 each),
// grid 2048 -> 32 waves/CU available. Cross-wave min via sortable-u32 LDS
// atomicMin (lossless bijection; filter only). Verify/epilogue semantics
// byte-identical to R18 (absmax 0.0 proven).
__launch_bounds__(256)
__attribute__((amdgpu_waves_per_eu(4, 8)))
__global__ void vq_kernel(const float* __restrict__ z,
                          const float* __restrict__ emb,
                          const float* __restrict__ se,
                          const half8* __restrict__ bpk,
                          float* __restrict__ out) {
    __shared__ float s_szz[BPX];
    __shared__ unsigned long long s_best[BPX];
    __shared__ unsigned s_pmin[BPX];
    __shared__ unsigned s_q[QCAP];
    __shared__ unsigned s_qn;
    __shared__ unsigned s_k[BPX];
    __shared__ float s_red[4];

    const int t = threadIdx.x, lane = t & 63, w = t >> 6;
    const int P0 = blockIdx.x * BPX;
    const int b = P0 >> 12, hw0 = P0 & 4095;
    const float* zbase = z + (size_t)b * CCH * HW + hw0;   // zbase[c*HW + pxl]

    if (t < BPX) {
        s_szz[t] = np_pairwise64_sq([&](int i) { return zbase[(size_t)i * HW + t]; });
        s_best[t] = ~0ULL;
        s_pmin[t] = 0xFFFFFFFFu;
    }
    if (t == 0) s_qn = 0u;
    __syncthreads();

    // A-frags (identical across the 4 waves; L1 catches the reuse):
    // slot (h,i) of reg s -> c = 16s+8h+i, row = lane&31 -> pixel P0+row
    const int row = lane & 31, h = lane >> 5;
    const float* zp = zbase + row;
    half8 A[4];
#pragma unroll
    for (int s = 0; s < 4; ++s)
#pragma unroll
        for (int i = 0; i < 8; ++i)
            A[s][i] = (_Float16)zp[(size_t)(16 * s + 8 * h + i) * HW];

    const int tile0 = w * TPW;                         // this wave's 8 tiles

    // ---- sweep 1: wave-local rmin over its 256 codes ----
    float rmin[16];
#pragma unroll
    for (int r = 0; r < 16; ++r) rmin[r] = 1e30f;

#pragma unroll 2
    for (int tt = 0; tt < TPW; ++tt) {
        const int tile = tile0 + tt;
        f32x16 acc;
#pragma unroll
        for (int r = 0; r < 16; ++r) acc[r] = 0.f;
#pragma unroll
        for (int s = 0; s < 4; ++s)
            acc = __builtin_amdgcn_mfma_f32_32x32x16_f16(
                A[s], bpk[(tile * 4 + s) * 64 + lane], acc, 0, 0, 0);
        const float sev = se[tile * 32 + row];
#pragma unroll
        for (int r = 0; r < 16; ++r)
            rmin[r] = fminf(rmin[r], __builtin_fmaf(-2.f, acc[r], sev));
    }
#pragma unroll
    for (int m = 1; m <= 16; m <<= 1)
#pragma unroll
        for (int r = 0; r < 16; ++r)
            rmin[r] = fminf(rmin[r], __shfl_xor(rmin[r], m, 64));

    // cross-wave combine (lanes 0 and 32 hold each half's reduced values)
    if (row == 0) {
#pragma unroll
        for (int r = 0; r < 16; ++r)
            atomicMin(&s_pmin[(r & 3) + 8 * (r >> 2) + 4 * h], f32_sort(rmin[r]));
    }
    __syncthreads();

    float gmin[16];
#pragma unroll
    for (int r = 0; r < 16; ++r)
        gmin[r] = f32_unsort(s_pmin[(r & 3) + 8 * (r >> 2) + 4 * h]);

    // ---- sweep 2: bit-identical recompute, push candidates <= gmin + THR ----
#pragma unroll 2
    for (int tt = 0; tt < TPW; ++tt) {
        const int tile = tile0 + tt;
        f32x16 acc;
#pragma unroll
        for (int r = 0; r < 16; ++r) acc[r] = 0.f;
#pragma unroll
        for (int s = 0; s < 4; ++s)
            acc = __builtin_amdgcn_mfma_f32_32x32x16_f16(
                A[s], bpk[(tile * 4 + s) * 64 + lane], acc, 0, 0, 0);
        const float sev = se[tile * 32 + row];
#pragma unroll
        for (int r = 0; r < 16; ++r) {
            const float key = __builtin_fmaf(-2.f, acc[r], sev);
            if (key <= gmin[r] + THRF) {
                const int pxl = (r & 3) + 8 * (r >> 2) + 4 * h;
                const unsigned k = (unsigned)(tile * 32 + row);
                const unsigned qi = atomicAdd(&s_qn, 1u);
                if (qi < QCAP) s_q[qi] = ((unsigned)pxl << 10) | k;
            }
        }
    }
    __syncthreads();

    // ---- exact verify: np fp32 chain (identical to R8), packed-u64 min ----
    {
        unsigned qn = s_qn; if (qn > QCAP) qn = QCAP;
        for (unsigned i = t; i < qn; i += 256) {
            const unsigned e = s_q[i];
            const int pxl = (int)(e >> 10), k = (int)(e & 1023u);
            const float* zc = zbase + pxl;
            const float* ek = emb + (size_t)k * CCH;
            float a = 0.f;
#pragma unroll 8
            for (int c = 0; c < CCH; ++c)
                a = __builtin_fmaf(zc[(size_t)c * HW], ek[c], a);  // same chain as R8
            const float d = __fsub_rn(__fadd_rn(s_szz[pxl], se[k]), __fadd_rn(a, a));
            atomicMin(&s_best[pxl],
                      ((unsigned long long)__float_as_uint(d) << 32) | (unsigned)k);
        }
    }
    __syncthreads();

    if (t < BPX) {
        const unsigned k = (unsigned)s_best[t];   // low 32 bits = first-index argmin
        s_k[t] = k;
        out[IDX_OFF + P0 + t] = (float)k;
    }
    __syncthreads();

    // ---- epilogue x2: EXACT R8 16-px tile procedure (same addend multiset) ----
#pragma unroll 1
    for (int ht = 0; ht < 2; ++ht) {
        float lsum = 0.f;
        {
            const int p = t & 15, g = t >> 4;
            const int pxl = (ht << 4) + p;
            const int k = (int)s_k[pxl];
#pragma unroll
            for (int u = 0; u < 4; ++u) {
                const int c = g + (u << 4);
                float e    = emb[(size_t)k * CCH + c];
                float zc   = zbase[(size_t)c * HW + pxl];
                float diff = __fsub_rn(e, zc);             // STE rounding as in R8
                out[((size_t)(b * CCH + c)) * HW + hw0 + pxl] = __fadd_rn(zc, diff);
                lsum = __builtin_fmaf(diff, diff, lsum);
            }
        }
#pragma unroll
        for (int off = 32; off > 0; off >>= 1) lsum += __shfl_down(lsum, off, 64);
        if (lane == 0) s_red[w] = lsum;
        __syncthreads();
        if (t == 0) {
            float v = (s_red[0] + s_red[1] + s_red[2] + s_red[3]) * (1.0f / (float)Q_ELEMS);
            atomicAdd(out + LOSS0_OFF, v);   // codebook_loss
            atomicAdd(out + LOSS1_OFF, v);   // commitment_loss (same forward value)
        }
        __syncthreads();
    }
}

extern "C" void kernel_launch(void* const* d_in, const int* in_sizes, int n_in,
                              void* d_out, int out_size, void* d_ws, size_t ws_size,
                              hipStream_t stream) {
    const float* z   = (const float*)d_in[0];
    const float* emb = (const float*)d_in[1];
    float* out = (float*)d_out;
    float* se  = (float*)d_ws;                     // 1024 f32
    half8* bpk = (half8*)(se + KCODE);             // 128 KB fp16 B-frags

    prep_kernel<<<dim3(32), dim3(256), 0, stream>>>(emb, se, bpk, out);
    vq_kernel<<<dim3(NPIX / BPX), dim3(256), 0, stream>>>(z, emb, se, bpk, out);
}

// Round 20
// 125.509 us; speedup vs baseline: 1.8542x; 1.5570x over previous
//
#include <hip/hip_runtime.h>

#define NPIX   65536          // B*H*W
#define CCH    64
#define KCODE  1024
#define HW     4096
#define Q_ELEMS 4194304
#define LOSS0_OFF 4194304
#define LOSS1_OFF 4194305
#define IDX_OFF   4194306
#define BPX    32             // pixels per block = one 32-row MFMA block
#define TPW    8              // code-tiles per wave (4 waves x 8 = all 32 tiles)
#define THRF   2e-3f          // ~25x the deterministic fp16 key-error bound
#define QCAP   512
#define NPART  4096           // 2048 blocks x 2 ht partial-loss slots

typedef _Float16 half8 __attribute__((ext_vector_type(8)));
typedef float    f32x16 __attribute__((ext_vector_type(16)));

// lossless order-preserving f32<->u32 bijection (for LDS atomicMin on keys)
__device__ __forceinline__ unsigned f32_sort(float f) {
    unsigned b = __float_as_uint(f);
    return (b & 0x80000000u) ? ~b : (b | 0x80000000u);
}
__device__ __forceinline__ float f32_unsort(unsigned u) {
    return (u & 0x80000000u) ? __uint_as_float(u & 0x7fffffffu)
                             : __uint_as_float(~u);
}

// numpy pairwise_sum middle branch for n=64 on squares (bit-exact np.sum(x*x))
template <typename F>
__device__ __forceinline__ float np_pairwise64_sq(F v) {
    float r[8];
#pragma unroll
    for (int j = 0; j < 8; ++j) r[j] = __fmul_rn(v(j), v(j));
#pragma unroll
    for (int i = 8; i < 64; i += 8) {
#pragma unroll
        for (int j = 0; j < 8; ++j)
            r[j] = __fadd_rn(r[j], __fmul_rn(v(i + j), v(i + j)));
    }
    return __fadd_rn(
        __fadd_rn(__fadd_rn(r[0], r[1]), __fadd_rn(r[2], r[3])),
        __fadd_rn(__fadd_rn(r[4], r[5]), __fadd_rn(r[6], r[7])));
}

// prep: se (np chain) + fp16 B-frag pack. Unchanged from the passing R19.
__global__ void prep_kernel(const float* __restrict__ emb,
                            float* __restrict__ se, half8* __restrict__ bpk,
                            float* __restrict__ out) {
    const int tid = blockIdx.x * 256 + threadIdx.x;   // 0..8191
    const int tile = tid >> 8, s = (tid >> 6) & 3, lane = tid & 63;
    const int n = tile * 32 + (lane & 31);
    const int h = lane >> 5;
    const float* er = emb + (size_t)n * CCH;
    half8 v;
#pragma unroll
    for (int i = 0; i < 8; ++i) v[i] = (_Float16)er[16 * s + 8 * h + i];
    bpk[(tile * 4 + s) * 64 + lane] = v;
    if (tid < KCODE) {
        const float* e = emb + (size_t)tid * CCH;
        se[tid] = np_pairwise64_sq([&](int i) { return e[i]; });
    }
    if (tid == 0) { out[LOSS0_OFF] = 0.f; out[LOSS1_OFF] = 0.f; }
}

// main: EXACT R19 structure (130.4us, absmax 0). ONLY change: the two
// same-address global atomicAdds per (block,ht) are replaced by ONE plain
// store of the partial to part[blockIdx*2+ht].
// R19 diagnosis: five different kernels (R3/R4/R8/R12/R19) all wall at
// 130.4-130.6us; R19's total issue is only ~26us. Common factor: 4096
// atomicAdds per loss address (all on ONE cacheline) -> L2 RMW serialization
// 4096 x ~65cy ~= 130us = the session-long floor. Addend multiset preserved;
// association change proven tolerated (absmax 0.0 across 4096x1 / 2048x2 /
// 512x8 nondeterministic-order shapes).
__launch_bounds__(256)
__attribute__((amdgpu_waves_per_eu(4, 8)))
__global__ void vq_kernel(const float* __restrict__ z,
                          const float* __restrict__ emb,
                          const float* __restrict__ se,
                          const half8* __restrict__ bpk,
                          float* __restrict__ part,
                          float* __restrict__ out) {
    __shared__ float s_szz[BPX];
    __shared__ unsigned long long s_best[BPX];
    __shared__ unsigned s_pmin[BPX];
    __shared__ unsigned s_q[QCAP];
    __shared__ unsigned s_qn;
    __shared__ unsigned s_k[BPX];
    __shared__ float s_red[4];

    const int t = threadIdx.x, lane = t & 63, w = t >> 6;
    const int P0 = blockIdx.x * BPX;
    const int b = P0 >> 12, hw0 = P0 & 4095;
    const float* zbase = z + (size_t)b * CCH * HW + hw0;   // zbase[c*HW + pxl]

    if (t < BPX) {
        s_szz[t] = np_pairwise64_sq([&](int i) { return zbase[(size_t)i * HW + t]; });
        s_best[t] = ~0ULL;
        s_pmin[t] = 0xFFFFFFFFu;
    }
    if (t == 0) s_qn = 0u;
    __syncthreads();

    // A-frags: slot (h,i) of reg s -> c = 16s+8h+i, row = lane&31 -> pixel P0+row
    const int row = lane & 31, h = lane >> 5;
    const float* zp = zbase + row;
    half8 A[4];
#pragma unroll
    for (int s = 0; s < 4; ++s)
#pragma unroll
        for (int i = 0; i < 8; ++i)
            A[s][i] = (_Float16)zp[(size_t)(16 * s + 8 * h + i) * HW];

    const int tile0 = w * TPW;                         // this wave's 8 tiles

    // ---- sweep 1: wave-local rmin over its 256 codes ----
    float rmin[16];
#pragma unroll
    for (int r = 0; r < 16; ++r) rmin[r] = 1e30f;

#pragma unroll 2
    for (int tt = 0; tt < TPW; ++tt) {
        const int tile = tile0 + tt;
        f32x16 acc;
#pragma unroll
        for (int r = 0; r < 16; ++r) acc[r] = 0.f;
#pragma unroll
        for (int s = 0; s < 4; ++s)
            acc = __builtin_amdgcn_mfma_f32_32x32x16_f16(
                A[s], bpk[(tile * 4 + s) * 64 + lane], acc, 0, 0, 0);
        const float sev = se[tile * 32 + row];
#pragma unroll
        for (int r = 0; r < 16; ++r)
            rmin[r] = fminf(rmin[r], __builtin_fmaf(-2.f, acc[r], sev));
    }
#pragma unroll
    for (int m = 1; m <= 16; m <<= 1)
#pragma unroll
        for (int r = 0; r < 16; ++r)
            rmin[r] = fminf(rmin[r], __shfl_xor(rmin[r], m, 64));

    // cross-wave combine (lanes 0 and 32 hold each half's reduced values)
    if (row == 0) {
#pragma unroll
        for (int r = 0; r < 16; ++r)
            atomicMin(&s_pmin[(r & 3) + 8 * (r >> 2) + 4 * h], f32_sort(rmin[r]));
    }
    __syncthreads();

    float gmin[16];
#pragma unroll
    for (int r = 0; r < 16; ++r)
        gmin[r] = f32_unsort(s_pmin[(r & 3) + 8 * (r >> 2) + 4 * h]);

    // ---- sweep 2: bit-identical recompute, push candidates <= gmin + THR ----
#pragma unroll 2
    for (int tt = 0; tt < TPW; ++tt) {
        const int tile = tile0 + tt;
        f32x16 acc;
#pragma unroll
        for (int r = 0; r < 16; ++r) acc[r] = 0.f;
#pragma unroll
        for (int s = 0; s < 4; ++s)
            acc = __builtin_amdgcn_mfma_f32_32x32x16_f16(
                A[s], bpk[(tile * 4 + s) * 64 + lane], acc, 0, 0, 0);
        const float sev = se[tile * 32 + row];
#pragma unroll
        for (int r = 0; r < 16; ++r) {
            const float key = __builtin_fmaf(-2.f, acc[r], sev);
            if (key <= gmin[r] + THRF) {
                const int pxl = (r & 3) + 8 * (r >> 2) + 4 * h;
                const unsigned k = (unsigned)(tile * 32 + row);
                const unsigned qi = atomicAdd(&s_qn, 1u);
                if (qi < QCAP) s_q[qi] = ((unsigned)pxl << 10) | k;
            }
        }
    }
    __syncthreads();

    // ---- exact verify: np fp32 chain (identical to R8), packed-u64 min ----
    {
        unsigned qn = s_qn; if (qn > QCAP) qn = QCAP;
        for (unsigned i = t; i < qn; i += 256) {
            const unsigned e = s_q[i];
            const int pxl = (int)(e >> 10), k = (int)(e & 1023u);
            const float* zc = zbase + pxl;
            const float* ek = emb + (size_t)k * CCH;
            float a = 0.f;
#pragma unroll 8
            for (int c = 0; c < CCH; ++c)
                a = __builtin_fmaf(zc[(size_t)c * HW], ek[c], a);  // same chain as R8
            const float d = __fsub_rn(__fadd_rn(s_szz[pxl], se[k]), __fadd_rn(a, a));
            atomicMin(&s_best[pxl],
                      ((unsigned long long)__float_as_uint(d) << 32) | (unsigned)k);
        }
    }
    __syncthreads();

    if (t < BPX) {
        const unsigned k = (unsigned)s_best[t];   // low 32 bits = first-index argmin
        s_k[t] = k;
        out[IDX_OFF + P0 + t] = (float)k;
    }
    __syncthreads();

    // ---- epilogue x2: EXACT R8 16-px tile procedure; partial stored, not atomic'd ----
#pragma unroll 1
    for (int ht = 0; ht < 2; ++ht) {
        float lsum = 0.f;
        {
            const int p = t & 15, g = t >> 4;
            const int pxl = (ht << 4) + p;
            const int k = (int)s_k[pxl];
#pragma unroll
            for (int u = 0; u < 4; ++u) {
                const int c = g + (u << 4);
                float e    = emb[(size_t)k * CCH + c];
                float zc   = zbase[(size_t)c * HW + pxl];
                float diff = __fsub_rn(e, zc);             // STE rounding as in R8
                out[((size_t)(b * CCH + c)) * HW + hw0 + pxl] = __fadd_rn(zc, diff);
                lsum = __builtin_fmaf(diff, diff, lsum);
            }
        }
#pragma unroll
        for (int off = 32; off > 0; off >>= 1) lsum += __shfl_down(lsum, off, 64);
        if (lane == 0) s_red[w] = lsum;
        __syncthreads();
        if (t == 0) {
            // same addend value as before; plain store instead of 2 atomicAdds
            part[(blockIdx.x << 1) + ht] =
                (s_red[0] + s_red[1] + s_red[2] + s_red[3]) * (1.0f / (float)Q_ELEMS);
        }
        __syncthreads();
    }
}

// final: sum the 4096 partials once, write both loss slots (deterministic tree)
__global__ void loss_kernel(const float* __restrict__ part,
                            float* __restrict__ out) {
    __shared__ float s[4];
    const int t = threadIdx.x;
    float x = 0.f;
#pragma unroll
    for (int i = 0; i < NPART / 256; ++i) x += part[t + (i << 8)];
#pragma unroll
    for (int off = 32; off > 0; off >>= 1) x += __shfl_down(x, off, 64);
    if ((t & 63) == 0) s[t >> 6] = x;
    __syncthreads();
    if (t == 0) {
        const float tot = (s[0] + s[1]) + (s[2] + s[3]);
        out[LOSS0_OFF] = tot;   // codebook_loss
        out[LOSS1_OFF] = tot;   // commitment_loss (same forward value)
    }
}

extern "C" void kernel_launch(void* const* d_in, const int* in_sizes, int n_in,
                              void* d_out, int out_size, void* d_ws, size_t ws_size,
                              hipStream_t stream) {
    const float* z   = (const float*)d_in[0];
    const float* emb = (const float*)d_in[1];
    float* out  = (float*)d_out;
    float* se   = (float*)d_ws;                    // 1024 f32
    half8* bpk  = (half8*)(se + KCODE);            // 128 KB fp16 B-frags
    float* part = (float*)((char*)d_ws + 4 * KCODE + 131072);  // 4096 f32

    prep_kernel<<<dim3(32), dim3(256), 0, stream>>>(emb, se, bpk, out);
    vq_kernel<<<dim3(NPIX / BPX), dim3(256), 0, stream>>>(z, emb, se, bpk, part, out);
    loss_kernel<<<dim3(1), dim3(256), 0, stream>>>(part, out);
}